// Round 1
// baseline (139.380 us; speedup 1.0000x reference)
//
#include <hip/hip_runtime.h>

typedef unsigned short ushort_t;
typedef ushort_t u16x8 __attribute__((ext_vector_type(8)));
typedef __bf16 bf16x8 __attribute__((ext_vector_type(8)));
typedef float f32x4 __attribute__((ext_vector_type(4)));

#define DET 736
#define NPAD 768

__device__ __forceinline__ ushort_t f2bf(float f) {
    unsigned u = __builtin_bit_cast(unsigned, f);
    u += 0x7FFFu + ((u >> 16) & 1u);
    return (ushort_t)(u >> 16);
}

// X[m][k] = sino[m][k] * 0.05*cos((k-367.5)*1e-3), cast to bf16
__global__ void prep_x(const float* __restrict__ sino, ushort_t* __restrict__ X, int total) {
    int idx = (blockIdx.x * blockDim.x + threadIdx.x) * 4;
    if (idx >= total) return;
    const float4 v = *(const float4*)(sino + idx);
    float vv[4] = {v.x, v.y, v.z, v.w};
    int j = idx % DET;  // 736 % 4 == 0, so 4-groups never straddle rows
    ushort_t oo[4];
#pragma unroll
    for (int t = 0; t < 4; ++t) {
        float w = 0.05f * cosf(((float)(j + t) - 367.5f) * 0.001f);
        oo[t] = f2bf(vv[t] * w);
    }
    ushort4 o; o.x = oo[0]; o.y = oo[1]; o.z = oo[2]; o.w = oo[3];
    *(ushort4*)(X + idx) = o;
}

// Bt[n][k] = f[k - n + 735]  (W symmetric => this is both W and W^T), rows n>=736 zero
__global__ void prep_bt(const float* __restrict__ filt, ushort_t* __restrict__ Bt) {
    int idx = blockIdx.x * blockDim.x + threadIdx.x;
    if (idx >= NPAD * DET) return;
    int n = idx / DET;
    int k = idx - n * DET;
    float v = (n < DET) ? filt[k - n + (DET - 1)] : 0.0f;  // index always in [0,1471)
    Bt[idx] = f2bf(v);
}

// OUT[M x 736] = X[M x 736] * W[736 x 736], bf16 MFMA, 128x128 tile, BK=32
__global__ __launch_bounds__(256) void gemm_bt(
    const ushort_t* __restrict__ A,   // M x DET bf16 bits
    const ushort_t* __restrict__ Bt,  // NPAD x DET bf16 bits
    float* __restrict__ C, int M)
{
    __shared__ ushort_t As[128 * 32];
    __shared__ ushort_t Bs[128 * 32];

    const int tid  = threadIdx.x;
    const int lane = tid & 63;
    const int warp = tid >> 6;   // 0..3
    const int wm   = warp & 1;   // 2x2 wave grid
    const int wn   = warp >> 1;
    const int quad = lane >> 4;  // 0..3
    const int l16  = lane & 15;

    const size_t row_a0 = (size_t)blockIdx.x * 128;
    const int    row_b0 = blockIdx.y * 128;

    f32x4 acc[4][4];
#pragma unroll
    for (int i = 0; i < 4; ++i)
#pragma unroll
        for (int jx = 0; jx < 4; ++jx)
            acc[i][jx] = (f32x4){0.f, 0.f, 0.f, 0.f};

    // staging: tile = 128 rows x 32 k = 512 chunks of 16B; 256 threads x 2 chunks
    const int c0 = tid, c1 = tid + 256;
    const int r0 = c0 >> 2, q0 = c0 & 3;
    const int r1 = c1 >> 2, q1 = c1 & 3;

    for (int k0 = 0; k0 < DET; k0 += 32) {
        __syncthreads();
        u16x8 a0 = *(const u16x8*)(A + (row_a0 + r0) * DET + k0 + q0 * 8);
        u16x8 a1 = *(const u16x8*)(A + (row_a0 + r1) * DET + k0 + q1 * 8);
        u16x8 b0 = *(const u16x8*)(Bt + (size_t)(row_b0 + r0) * DET + k0 + q0 * 8);
        u16x8 b1 = *(const u16x8*)(Bt + (size_t)(row_b0 + r1) * DET + k0 + q1 * 8);
        *(u16x8*)(As + c0 * 8) = a0;
        *(u16x8*)(As + c1 * 8) = a1;
        *(u16x8*)(Bs + c0 * 8) = b0;
        *(u16x8*)(Bs + c1 * 8) = b1;
        __syncthreads();

        u16x8 af[4], bfr[4];
#pragma unroll
        for (int mi = 0; mi < 4; ++mi)
            af[mi] = *(const u16x8*)(As + (wm * 64 + mi * 16 + l16) * 32 + quad * 8);
#pragma unroll
        for (int ni = 0; ni < 4; ++ni)
            bfr[ni] = *(const u16x8*)(Bs + (wn * 64 + ni * 16 + l16) * 32 + quad * 8);
#pragma unroll
        for (int mi = 0; mi < 4; ++mi)
#pragma unroll
            for (int ni = 0; ni < 4; ++ni)
                acc[mi][ni] = __builtin_amdgcn_mfma_f32_16x16x32_bf16(
                    __builtin_bit_cast(bf16x8, af[mi]),
                    __builtin_bit_cast(bf16x8, bfr[ni]),
                    acc[mi][ni], 0, 0, 0);
    }

    // epilogue: C/D layout col=lane&15, row=quad*4+reg [verified mapping]
#pragma unroll
    for (int mi = 0; mi < 4; ++mi) {
#pragma unroll
        for (int ni = 0; ni < 4; ++ni) {
            int colg = row_b0 + wn * 64 + ni * 16 + l16;
            if (colg < DET) {
#pragma unroll
                for (int r = 0; r < 4; ++r) {
                    size_t rowg = row_a0 + wm * 64 + mi * 16 + quad * 4 + r;
                    C[rowg * DET + colg] = acc[mi][ni][r];
                }
            }
        }
    }
}

extern "C" void kernel_launch(void* const* d_in, const int* in_sizes, int n_in,
                              void* d_out, int out_size, void* d_ws, size_t ws_size,
                              hipStream_t stream) {
    const float* sino = (const float*)d_in[0];
    const float* filt = (const float*)d_in[1];
    int total = in_sizes[0];     // 16*1*1152*736 = 13,565,952
    int M = total / DET;         // 18432

    ushort_t* Xbf = (ushort_t*)d_ws;
    ushort_t* Btb = Xbf + (size_t)total;   // +27.1 MB (16B-aligned)
    float* out = (float*)d_out;

    prep_x<<<(total / 4 + 255) / 256, 256, 0, stream>>>(sino, Xbf, total);
    prep_bt<<<(NPAD * DET + 255) / 256, 256, 0, stream>>>(filt, Btb);

    dim3 grid(M / 128, NPAD / 128);  // 144 x 6
    gemm_bt<<<grid, 256, 0, stream>>>(Xbf, Btb, out, M);
}